// Round 7
// baseline (403.593 us; speedup 1.0000x reference)
//
#include <hip/hip_runtime.h>

// rnn_lyapunov: B=64,T=2048,NIN=64,NH=512,NOUT=64
// Time-parallel chunked RNN, W=5 warmup (contraction ||A||~0.3).
// R15 = R14 with the REAL VGPR ceiling lifted. R12-R14 post-mortem: the
// allocator caps VGPRs at the LDS-permitted occupancy. At LDS=75,776 B two
// 16-wave blocks fit per CU -> backend targets 8 waves/SIMD -> 64-VGPR cap
// (512/8), independent of __launch_bounds__ (R14 proved that). Our ~105 live
// VGPRs spilled -> FETCH 566MB scratch traffic. Fix: ST_H 520->584 pushes
// LDS to 83,968 B (> 160K/2) -> only 1 block/CU -> 4 waves/SIMD target ->
// 128-VGPR budget. Grid is 256 blocks / 256 CUs so the lost 2nd block was
// worthless. Bank phase preserved: (ST_H/2)%32 == 4 for both 520 and 584.
// Body identical to R14: kk=0..3 A-fragments both tiles + all W_ih resident
// (48 VGPR, -30% L2 stream/step); named vars only, literal kk macros (R12
// lesson); LDS-only step barrier. 16x16x32 MFMA / f32x4 accs only.

#define T_LEN 2048
#define H_DIM 512
#define N_IN  64
#define N_OUT 64
#define L_CH  16
#define M_B   32                 // batch rows per block (batch-split 2)
#define W_UP  5
#define S_FULL (W_UP + L_CH)     // 21 full steps (s=0..20) + final head-only
#define ST_H  584                // h_buf row stride (shorts): 16B-aligned,
                                 // (584/2)%32==4 (same bank phase as 520);
                                 // sized so LDS>81920B -> 1 block/CU -> 128 VGPR
#define ST_U  72
#define K2f   2.8853900817779268f   // 2*log2(e), folded into Apk/WihPk/bias

typedef __attribute__((ext_vector_type(8))) short short8;   // 8 bf16 in 4 VGPRs
typedef __attribute__((ext_vector_type(4))) float f32x4;

__device__ __forceinline__ unsigned short f2bf(float f) {
  union { float f; unsigned u; } v; v.f = f;
  return (unsigned short)((v.u + 0x7FFFu + ((v.u >> 16) & 1u)) >> 16);  // RNE
}

#if __has_builtin(__builtin_amdgcn_cvt_pk_bf16_f32)
__device__ __forceinline__ unsigned pack2bf(float a, float b) {
  auto r = __builtin_amdgcn_cvt_pk_bf16_f32(a, b);
  unsigned u; __builtin_memcpy(&u, &r, 4);
  return u;
}
#else
__device__ __forceinline__ unsigned pack2bf(float a, float b) {
  return (unsigned)f2bf(a) | ((unsigned)f2bf(b) << 16);
}
#endif

#if __has_builtin(__builtin_amdgcn_exp2f)
#define EXP2(x) __builtin_amdgcn_exp2f(x)
#else
#define EXP2(x) exp2f(x)
#endif

// z = 2*log2(e)*x (prescale in weights): tanh(x) = 1 - 2/(2^z + 1)
__device__ __forceinline__ float tanh_z(float z) {
  float r = __builtin_amdgcn_rcpf(EXP2(z) + 1.f);
  return __builtin_fmaf(-2.f, r, 1.f);   // z->+inf: 1; z->-inf: -1
}

#define MFMA(a, b, acc) __builtin_amdgcn_mfma_f32_16x16x32_bf16(a, b, acc, 0, 0, 0)

// LDS-only step barrier: drain LDS writes, keep global loads/stores in flight.
__device__ __forceinline__ void step_barrier() {
  __builtin_amdgcn_sched_barrier(0);
  asm volatile("s_waitcnt lgkmcnt(0)" ::: "memory");
  __builtin_amdgcn_s_barrier();
  __builtin_amdgcn_sched_barrier(0);
}

// ---- pack weights into MFMA A-operand fragment layout ----------------------
// A-frag 16x16x32: lane L holds A[m = 16*mt + (L&15)][k = 32*kk + 8*(L>>4) + j]
// Apk  [kk=16][mt=32][lane][8] : K2*W_hh[m][k]*omega[k]^2
// WihPk[kk= 2][mt=32][lane][8] : K2*W_ih[m][k]
// WlinPk[kk=16][mt=4][lane][8] : W_lin[m][k]   (unscaled)
__global__ __launch_bounds__(256) void pack_kernel(
    const float* __restrict__ W_ih, const float* __restrict__ W_hh,
    const float* __restrict__ omega, const float* __restrict__ W_lin,
    unsigned short* __restrict__ Apk, unsigned short* __restrict__ WihPk,
    unsigned short* __restrict__ WlinPk)
{
  __shared__ unsigned short Lh[512][40];
  const int tid = threadIdx.x, bid = blockIdx.x;
  const int l32 = tid & 31, nr = tid >> 5;

  if (bid < 16) {                            // ---- A: kk = bid
    const int k0 = bid * 32;
    const float om = omega[k0 + l32];
    const float om2 = om * om * K2f;
    for (int n = nr; n < 512; n += 8)
      Lh[n][l32] = f2bf(W_hh[(size_t)n * 512 + k0 + l32] * om2);
    __syncthreads();
    const int mt = tid >> 3, lane0 = (tid & 7) * 8;
    unsigned short* dst = Apk + (size_t)bid * 16384 + (size_t)tid * 64;
    #pragma unroll
    for (int l = 0; l < 8; l++) {
      const int lane = lane0 + l, cc = lane & 15, qq = lane >> 4;
      *(short8*)(dst + l * 8) = *(const short8*)&Lh[mt * 16 + cc][qq * 8];
    }
  } else if (bid < 18) {                     // ---- W_ih: kk = bid-16
    const int kk = bid - 16, k0 = kk * 32;
    for (int n = nr; n < 512; n += 8)
      Lh[n][l32] = f2bf(W_ih[(size_t)n * 64 + k0 + l32] * K2f);
    __syncthreads();
    const int mt = tid >> 3, lane0 = (tid & 7) * 8;
    unsigned short* dst = WihPk + (size_t)kk * 16384 + (size_t)tid * 64;
    #pragma unroll
    for (int l = 0; l < 8; l++) {
      const int lane = lane0 + l, cc = lane & 15, qq = lane >> 4;
      *(short8*)(dst + l * 8) = *(const short8*)&Lh[mt * 16 + cc][qq * 8];
    }
  } else {                                   // ---- W_lin: kk = bid-18
    const int kk = bid - 18, k0 = kk * 32;
    for (int n = nr; n < 64; n += 8)
      Lh[n][l32] = f2bf(W_lin[(size_t)n * 512 + k0 + l32]);
    __syncthreads();
    const int mt = tid >> 6, lane = tid & 63, cc = lane & 15, qq = lane >> 4;
    unsigned short* dst = WlinPk + (size_t)kk * 2048 + (size_t)tid * 8;
    *(short8*)dst = *(const short8*)&Lh[mt * 16 + cc][qq * 8];
  }
}

// ---- kk-step macros: literal kk only, named accumulators/residents ---------
#define LD_H(kk, bt) (*(const short8*)&h_buf[cur][(bt)*16 + c][(kk)*32 + q*8])

#define KK_R(kk, A0, A1) do {                                               \
    const short8 hf0 = LD_H(kk, 0);                                         \
    const short8 hf1 = LD_H(kk, 1);                                         \
    acc00 = MFMA(A0, hf0, acc00);                                           \
    acc10 = MFMA(A1, hf0, acc10);                                           \
    acc01 = MFMA(A0, hf1, acc01);                                           \
    acc11 = MFMA(A1, hf1, acc11);                                           \
  } while (0)

#define KK_S(kk) do {                                                       \
    const short8 a0s = *(const short8*)(apA + (size_t)(kk) * 16384);        \
    const short8 a1s = *(const short8*)(apA + (size_t)(kk) * 16384 + 512);  \
    KK_R(kk, a0s, a1s);                                                     \
  } while (0)

#define KK_RH(kk, A0, A1) do {                                              \
    const short8 hf0 = LD_H(kk, 0);                                         \
    const short8 hf1 = LD_H(kk, 1);                                         \
    const short8 aw  = *(const short8*)(lpA + (size_t)(kk) * 2048);         \
    acc00 = MFMA(A0, hf0, acc00);                                           \
    acc10 = MFMA(A1, hf0, acc10);                                           \
    aL0   = MFMA(aw, hf0, aL0);                                             \
    acc01 = MFMA(A0, hf1, acc01);                                           \
    acc11 = MFMA(A1, hf1, acc11);                                           \
    aL1   = MFMA(aw, hf1, aL1);                                             \
  } while (0)

#define KK_SH(kk) do {                                                      \
    const short8 a0s = *(const short8*)(apA + (size_t)(kk) * 16384);        \
    const short8 a1s = *(const short8*)(apA + (size_t)(kk) * 16384 + 512);  \
    KK_RH(kk, a0s, a1s);                                                    \
  } while (0)

#define EPI(mt, bt, ACC, BS) do {                                           \
    const unsigned lo = pack2bf(tanh_z(ACC[0] + BS[0]),                     \
                                tanh_z(ACC[1] + BS[1]));                    \
    const unsigned hi = pack2bf(tanh_z(ACC[2] + BS[2]),                     \
                                tanh_z(ACC[3] + BS[3]));                    \
    unsigned* d = (unsigned*)&h_buf[nxt][(bt)*16 + c][(2*w + (mt))*16 + q*4]; \
    d[0] = lo; d[1] = hi;                                                   \
  } while (0)

// ---- main time-parallel recurrence kernel ----------------------------------
// 256 blocks = 128 t-chunks x 2 batch-halves. 1024 threads = 16 waves
// (1 block/CU by LDS: 83,968 B -> backend targets 4 waves/SIMD -> 128 VGPR
// budget; this is THE fix for R12-R14's spills). Wave w owns hidden A-tiles
// {2w,2w+1}, batch tiles 0-1, named accs acc00..acc11. Residents:
// rA0_0..3/rA1_0..3 (A kk=0..3) + rW*_* (all W_ih) = 48 VGPR, loaded once
// -> 30% less L2 stream per step; kk 0..3 need zero loads (covers
// post-barrier latency). Waves 0-3 also own W_lin tile w (streamed).
// One LDS-only barrier per step.
__global__ __launch_bounds__(1024, 1) void rnn_kernel(
    const float* __restrict__ u, const float* __restrict__ b_ih,
    const float* __restrict__ b_hh, const float* __restrict__ b_lin,
    const unsigned short* __restrict__ Apk,
    const unsigned short* __restrict__ WihPk,
    const unsigned short* __restrict__ WlinPk,
    float* __restrict__ out)
{
  __shared__ __align__(16) unsigned short h_buf[2][M_B][ST_H];  // 74,752 B
  __shared__ __align__(16) unsigned short u_buf[2][M_B][ST_U];  //  9,216 B

  const int tid = threadIdx.x;
  const int w = tid >> 6, lane = tid & 63, q = lane >> 4, c = lane & 15;
  const int bh = blockIdx.x >> 7;            // batch half (0/1)
  const int t0 = (blockIdx.x & 127) * L_CH;  // t-chunk origin
  const int B0 = bh * M_B;                   // global batch row base
  const bool hw = (w < 4);                   // head wave (one per SIMD)
  const int lt = w & 3;                      // head W_lin tile (valid when hw)

  // biases in registers (prescaled by K2); b_lin raw
  f32x4 bsum0, bsum1;
  {
    const int n0 = (2 * w) * 16 + q * 4;
    const f32x4 b0 = *(const f32x4*)(b_ih + n0) + *(const f32x4*)(b_hh + n0);
    bsum0 = (f32x4){b0[0] * K2f, b0[1] * K2f, b0[2] * K2f, b0[3] * K2f};
    const int n1 = (2 * w + 1) * 16 + q * 4;
    const f32x4 b1 = *(const f32x4*)(b_ih + n1) + *(const f32x4*)(b_hh + n1);
    bsum1 = (f32x4){b1[0] * K2f, b1[1] * K2f, b1[2] * K2f, b1[3] * K2f};
  }
  const f32x4 blin4 = *(const f32x4*)(b_lin + lt * 16 + q * 4);

  for (int i = tid; i < M_B * ST_H / 2; i += 1024) ((unsigned*)h_buf[0])[i] = 0;
  {    // stage u for step 0: tau(0) = max(t0 - W, 0); 2 floats/thread
    int t = t0 - W_UP; if (t < 0) t = 0;
    const int row = tid >> 5, cb = (tid & 31) * 2;
    const float* src = u + ((size_t)(B0 + row) * T_LEN + t) * N_IN + cb;
    *(unsigned*)&u_buf[0][row][cb] = pack2bf(src[0], src[1]);
  }

  const unsigned short* apA = Apk    + ((size_t)(2 * w) * 64 + lane) * 8;
  const unsigned short* wpA = WihPk  + ((size_t)(2 * w) * 64 + lane) * 8;
  const unsigned short* lpA = WlinPk + ((size_t)lt * 64 + lane) * 8;

  // ---- resident fragments: loaded ONCE, named, never reassigned ----
  const short8 rW0_0 = *(const short8*)(wpA);
  const short8 rW1_0 = *(const short8*)(wpA + 512);
  const short8 rW0_1 = *(const short8*)(wpA + 16384);
  const short8 rW1_1 = *(const short8*)(wpA + 16384 + 512);
  const short8 rA0_0 = *(const short8*)(apA);
  const short8 rA1_0 = *(const short8*)(apA + 512);
  const short8 rA0_1 = *(const short8*)(apA + 1 * 16384);
  const short8 rA1_1 = *(const short8*)(apA + 1 * 16384 + 512);
  const short8 rA0_2 = *(const short8*)(apA + 2 * 16384);
  const short8 rA1_2 = *(const short8*)(apA + 2 * 16384 + 512);
  const short8 rA0_3 = *(const short8*)(apA + 3 * 16384);
  const short8 rA1_3 = *(const short8*)(apA + 3 * 16384 + 512);

  __syncthreads();

  for (int s = 0; s < S_FULL; s++) {
    const int cur = s & 1, nxt = cur ^ 1;

    // prefetch next step's u into registers (coalesced)
    float up0, up1;
    {
      int tn = t0 - W_UP + s + 1;
      tn = tn < 0 ? 0 : (tn > T_LEN - 1 ? T_LEN - 1 : tn);
      const int row = tid >> 5, cb = (tid & 31) * 2;
      const float* src = u + ((size_t)(B0 + row) * T_LEN + tn) * N_IN + cb;
      up0 = src[0]; up1 = src[1];
    }

    f32x4 acc00 = {0.f, 0.f, 0.f, 0.f}, acc01 = {0.f, 0.f, 0.f, 0.f};
    f32x4 acc10 = {0.f, 0.f, 0.f, 0.f}, acc11 = {0.f, 0.f, 0.f, 0.f};

    // ---- A x h (K=512): kk 0..3 resident, 4..15 streamed from L2 ----
    if (hw) {
      f32x4 aL0 = {0.f, 0.f, 0.f, 0.f}, aL1 = {0.f, 0.f, 0.f, 0.f};
      KK_RH(0, rA0_0, rA1_0);
      KK_RH(1, rA0_1, rA1_1);
      KK_RH(2, rA0_2, rA1_2);
      KK_RH(3, rA0_3, rA1_3);
      KK_SH(4);  KK_SH(5);  KK_SH(6);  KK_SH(7);
      KK_SH(8);  KK_SH(9);  KK_SH(10); KK_SH(11);
      KK_SH(12); KK_SH(13); KK_SH(14); KK_SH(15);
      // head store: out_t = W_lin*h^s + b_lin, t = t0 + s - W_UP - 1
      if (s > W_UP) {
        const int t = t0 + s - W_UP - 1;
        const f32x4 r0 = aL0 + blin4;
        float* op0 = out + ((size_t)(B0 + c) * T_LEN + t) * N_OUT + lt * 16 + q * 4;
        *(f32x4*)op0 = r0;
        const f32x4 r1 = aL1 + blin4;
        float* op1 = out + ((size_t)(B0 + 16 + c) * T_LEN + t) * N_OUT + lt * 16 + q * 4;
        *(f32x4*)op1 = r1;
      }
    } else {
      KK_R(0, rA0_0, rA1_0);
      KK_R(1, rA0_1, rA1_1);
      KK_R(2, rA0_2, rA1_2);
      KK_R(3, rA0_3, rA1_3);
      KK_S(4);  KK_S(5);  KK_S(6);  KK_S(7);
      KK_S(8);  KK_S(9);  KK_S(10); KK_S(11);
      KK_S(12); KK_S(13); KK_S(14); KK_S(15);
    }

    // ---- + W_ih x u_t: K = 64, resident weights, same accumulators ----
    {
      const short8 uf0_0 = *(const short8*)&u_buf[cur][c][q * 8];
      const short8 uf1_0 = *(const short8*)&u_buf[cur][16 + c][q * 8];
      acc00 = MFMA(rW0_0, uf0_0, acc00);
      acc10 = MFMA(rW1_0, uf0_0, acc10);
      acc01 = MFMA(rW0_0, uf1_0, acc01);
      acc11 = MFMA(rW1_0, uf1_0, acc11);
      const short8 uf0_1 = *(const short8*)&u_buf[cur][c][32 + q * 8];
      const short8 uf1_1 = *(const short8*)&u_buf[cur][16 + c][32 + q * 8];
      acc00 = MFMA(rW0_1, uf0_1, acc00);
      acc10 = MFMA(rW1_1, uf0_1, acc10);
      acc01 = MFMA(rW0_1, uf1_1, acc01);
      acc11 = MFMA(rW1_1, uf1_1, acc11);
    }

    // ---- epilogue: h_new = tanh_z(acc + bias) -> h_buf[nxt] (b64 writes) ----
    EPI(0, 0, acc00, bsum0);
    EPI(0, 1, acc01, bsum0);
    EPI(1, 0, acc10, bsum1);
    EPI(1, 1, acc11, bsum1);
    {
      const int row = tid >> 5, cb = (tid & 31) * 2;
      *(unsigned*)&u_buf[nxt][row][cb] = pack2bf(up0, up1);
    }
    step_barrier();   // LDS-only drain: global loads/stores span the barrier
  }

  // ---- final head-only step: waves 0-3 consume h^21 (buf [S_FULL&1]) ----
  if (hw) {
    const int cf = S_FULL & 1;
    f32x4 aL0 = {0.f, 0.f, 0.f, 0.f}, aL1 = {0.f, 0.f, 0.f, 0.f};
#define KK_FIN(kk) do {                                                     \
      const short8 aw  = *(const short8*)(lpA + (size_t)(kk) * 2048);       \
      const short8 hf0 = *(const short8*)&h_buf[cf][c][(kk)*32 + q*8];      \
      const short8 hf1 = *(const short8*)&h_buf[cf][16 + c][(kk)*32 + q*8]; \
      aL0 = MFMA(aw, hf0, aL0);                                             \
      aL1 = MFMA(aw, hf1, aL1);                                             \
    } while (0)
    KK_FIN(0);  KK_FIN(1);  KK_FIN(2);  KK_FIN(3);
    KK_FIN(4);  KK_FIN(5);  KK_FIN(6);  KK_FIN(7);
    KK_FIN(8);  KK_FIN(9);  KK_FIN(10); KK_FIN(11);
    KK_FIN(12); KK_FIN(13); KK_FIN(14); KK_FIN(15);
#undef KK_FIN
    const int t = t0 + L_CH - 1;
    const f32x4 r0 = aL0 + blin4;
    float* op0 = out + ((size_t)(B0 + c) * T_LEN + t) * N_OUT + lt * 16 + q * 4;
    *(f32x4*)op0 = r0;
    const f32x4 r1 = aL1 + blin4;
    float* op1 = out + ((size_t)(B0 + 16 + c) * T_LEN + t) * N_OUT + lt * 16 + q * 4;
    *(f32x4*)op1 = r1;
  }
}

extern "C" void kernel_launch(void* const* d_in, const int* in_sizes, int n_in,
                              void* d_out, int out_size, void* d_ws, size_t ws_size,
                              hipStream_t stream) {
  const float* u     = (const float*)d_in[0];
  const float* W_ih  = (const float*)d_in[1];
  const float* W_hh  = (const float*)d_in[2];
  const float* b_ih  = (const float*)d_in[3];
  const float* b_hh  = (const float*)d_in[4];
  const float* omega = (const float*)d_in[5];
  const float* W_lin = (const float*)d_in[6];
  const float* b_lin = (const float*)d_in[7];
  float* out = (float*)d_out;

  unsigned short* Apk    = (unsigned short*)d_ws;                 // 512*512 bf16
  unsigned short* WihPk  = Apk + (size_t)H_DIM * H_DIM;           // 512*64
  unsigned short* WlinPk = WihPk + (size_t)H_DIM * N_IN;          // 64*512

  pack_kernel<<<34, 256, 0, stream>>>(W_ih, W_hh, omega, W_lin, Apk, WihPk, WlinPk);
  rnn_kernel<<<(T_LEN / L_CH) * 2, 1024, 0, stream>>>(u, b_ih, b_hh, b_lin,
                                                      Apk, WihPk, WlinPk, out);
}

// Round 8
// 381.555 us; speedup vs baseline: 1.0578x; 1.0578x over previous
//
#include <hip/hip_runtime.h>

// rnn_lyapunov: B=64,T=2048,NIN=64,NH=512,NOUT=64
// Time-parallel chunked RNN, W=5 warmup (contraction ||A||~0.3).
// R16 (R11 skeleton + per-wave global_load_lds A-stream pipeline).
// R12-R15 lesson: 1024-thread MFMA kernels get ~64 arch VGPRs on this
// toolchain (launch_bounds / LDS occupancy / named vars all failed to lift
// it) -> register residency of weights is impossible. Instead overlap the
// serial ~3.9us/step A+W_ih L2 stream with MFMA using the zero-VGPR path:
// per-wave 2-slot LDS ring fed by global_load_lds (L2->LDS DMA), consumed
// by ds_read_b128. 18 contents/step (16 A-kk + 2 W_ih-kk); stage content
// kk+2 after consuming kk (wrap mod 18 primes the NEXT step across the
// lgkm-only barrier -> loads stay in flight, never drained to 0 in the
// loop). Counted vmcnt waits are exact: loop contains only stage ops (asm
// memory clobbers fence compiler vmem out); u-prefetch issued post-loop one
// step ahead; head stores post-loop. 16x16x32 MFMA / f32x4 accs only.

#define T_LEN 2048
#define H_DIM 512
#define N_IN  64
#define N_OUT 64
#define L_CH  16
#define M_B   32                 // batch rows per block (batch-split 2)
#define W_UP  5
#define S_FULL (W_UP + L_CH)     // 21 full steps (s=0..20) + final head-only
#define ST_H  520                // h_buf row stride (shorts): 16B-aligned
#define ST_U  72
#define K2f   2.8853900817779268f   // 2*log2(e), folded into Apk/WihPk/bias

typedef __attribute__((ext_vector_type(8))) short short8;   // 8 bf16 in 4 VGPRs
typedef __attribute__((ext_vector_type(4))) float f32x4;
typedef __attribute__((ext_vector_type(2))) float f32x2;

__device__ __forceinline__ unsigned short f2bf(float f) {
  union { float f; unsigned u; } v; v.f = f;
  return (unsigned short)((v.u + 0x7FFFu + ((v.u >> 16) & 1u)) >> 16);  // RNE
}

#if __has_builtin(__builtin_amdgcn_cvt_pk_bf16_f32)
__device__ __forceinline__ unsigned pack2bf(float a, float b) {
  auto r = __builtin_amdgcn_cvt_pk_bf16_f32(a, b);
  unsigned u; __builtin_memcpy(&u, &r, 4);
  return u;
}
#else
__device__ __forceinline__ unsigned pack2bf(float a, float b) {
  return (unsigned)f2bf(a) | ((unsigned)f2bf(b) << 16);
}
#endif

#if __has_builtin(__builtin_amdgcn_exp2f)
#define EXP2(x) __builtin_amdgcn_exp2f(x)
#else
#define EXP2(x) exp2f(x)
#endif

// z = 2*log2(e)*x (prescale in weights): tanh(x) = 1 - 2/(2^z + 1)
__device__ __forceinline__ float tanh_z(float z) {
  float r = __builtin_amdgcn_rcpf(EXP2(z) + 1.f);
  return __builtin_fmaf(-2.f, r, 1.f);   // z->+inf: 1; z->-inf: -1
}

#define MFMA(a, b, acc) __builtin_amdgcn_mfma_f32_16x16x32_bf16(a, b, acc, 0, 0, 0)

// L2 -> LDS DMA: 64 lanes x 16B; lds dest = wave-uniform base + lane*16,
// global src per-lane. Zero VGPR data path.
#if __has_builtin(__builtin_amdgcn_global_load_lds)
__device__ __forceinline__ void gload_lds16(const unsigned short* g,
                                            unsigned short* l, int lane) {
  (void)lane;
  __builtin_amdgcn_global_load_lds(
      (const __attribute__((address_space(1))) unsigned int*)(const void*)g,
      (__attribute__((address_space(3))) unsigned int*)(void*)l, 16, 0, 0);
}
#else
__device__ __forceinline__ void gload_lds16(const unsigned short* g,
                                            unsigned short* l, int lane) {
  *(short8*)((char*)l + lane * 16) = *(const short8*)g;   // correctness fallback
}
#endif

#define VMW(n) asm volatile("s_waitcnt vmcnt(" #n ")" ::: "memory")
#define LGK0   asm volatile("s_waitcnt lgkmcnt(0)" ::: "memory")

// LDS-only step barrier: drain LDS ops, keep global loads/DMA in flight.
__device__ __forceinline__ void step_barrier() {
  LGK0;
  __builtin_amdgcn_s_barrier();
}

// ---- pack weights into MFMA A-operand fragment layout ----------------------
// A-frag 16x16x32: lane L holds A[m = 16*mt + (L&15)][k = 32*kk + 8*(L>>4) + j]
// Apk  [kk=16][mt=32][lane][8] : K2*W_hh[m][k]*omega[k]^2
// WihPk[kk= 2][mt=32][lane][8] : K2*W_ih[m][k]
// WlinPk[kk=16][mt=4][lane][8] : W_lin[m][k]   (unscaled)
__global__ __launch_bounds__(256) void pack_kernel(
    const float* __restrict__ W_ih, const float* __restrict__ W_hh,
    const float* __restrict__ omega, const float* __restrict__ W_lin,
    unsigned short* __restrict__ Apk, unsigned short* __restrict__ WihPk,
    unsigned short* __restrict__ WlinPk)
{
  __shared__ unsigned short Lh[512][40];
  const int tid = threadIdx.x, bid = blockIdx.x;
  const int l32 = tid & 31, nr = tid >> 5;

  if (bid < 16) {                            // ---- A: kk = bid
    const int k0 = bid * 32;
    const float om = omega[k0 + l32];
    const float om2 = om * om * K2f;
    for (int n = nr; n < 512; n += 8)
      Lh[n][l32] = f2bf(W_hh[(size_t)n * 512 + k0 + l32] * om2);
    __syncthreads();
    const int mt = tid >> 3, lane0 = (tid & 7) * 8;
    unsigned short* dst = Apk + (size_t)bid * 16384 + (size_t)tid * 64;
    #pragma unroll
    for (int l = 0; l < 8; l++) {
      const int lane = lane0 + l, cc = lane & 15, qq = lane >> 4;
      *(short8*)(dst + l * 8) = *(const short8*)&Lh[mt * 16 + cc][qq * 8];
    }
  } else if (bid < 18) {                     // ---- W_ih: kk = bid-16
    const int kk = bid - 16, k0 = kk * 32;
    for (int n = nr; n < 512; n += 8)
      Lh[n][l32] = f2bf(W_ih[(size_t)n * 64 + k0 + l32] * K2f);
    __syncthreads();
    const int mt = tid >> 3, lane0 = (tid & 7) * 8;
    unsigned short* dst = WihPk + (size_t)kk * 16384 + (size_t)tid * 64;
    #pragma unroll
    for (int l = 0; l < 8; l++) {
      const int lane = lane0 + l, cc = lane & 15, qq = lane >> 4;
      *(short8*)(dst + l * 8) = *(const short8*)&Lh[mt * 16 + cc][qq * 8];
    }
  } else {                                   // ---- W_lin: kk = bid-18
    const int kk = bid - 18, k0 = kk * 32;
    for (int n = nr; n < 64; n += 8)
      Lh[n][l32] = f2bf(W_lin[(size_t)n * 512 + k0 + l32]);
    __syncthreads();
    const int mt = tid >> 6, lane = tid & 63, cc = lane & 15, qq = lane >> 4;
    unsigned short* dst = WlinPk + (size_t)kk * 2048 + (size_t)tid * 8;
    *(short8*)dst = *(const short8*)&Lh[mt * 16 + cc][qq * 8];
  }
}

// ---- stage macros (contents: 0..15 = A kk, 16..17 = W_ih kk-16) ------------
#define ST_A(c, SD) do { \
    gload_lds16(apG + (size_t)(c) * 16384, SD, lane); \
    gload_lds16(apG + (size_t)(c) * 16384 + 512, (SD) + 512, lane); } while (0)
#define ST_W(c, SD) do { \
    gload_lds16(wpG + (size_t)(c) * 16384, SD, lane); \
    gload_lds16(wpG + (size_t)(c) * 16384 + 512, (SD) + 512, lane); } while (0)
#define ST_L(c, SD) gload_lds16(lpG + (size_t)(c) * 2048, SD, lane)

#define LD_H(kk, bt) (*(const short8*)&h_buf[cur][(bt)*16 + c][(kk)*32 + q*8])

// A-phase iteration (h operand). RB = per-lane slot read base. STG staged
// AFTER lgkmcnt(0) so the ds_read data is in VGPRs before the DMA overwrites.
#define KA(kk, RB, STG) do { \
    const short8 hf0 = LD_H(kk, 0); \
    const short8 hf1 = LD_H(kk, 1); \
    const short8 a0 = *(const short8*)(RB); \
    const short8 a1 = *(const short8*)((RB) + 512); \
    LGK0; \
    STG; \
    acc00 = MFMA(a0, hf0, acc00); \
    acc10 = MFMA(a1, hf0, acc10); \
    acc01 = MFMA(a0, hf1, acc01); \
    acc11 = MFMA(a1, hf1, acc11); } while (0)

// head variant: + W_lin fragment from W_ring
#define KAH(kk, RB, WRB, STG) do { \
    const short8 hf0 = LD_H(kk, 0); \
    const short8 hf1 = LD_H(kk, 1); \
    const short8 a0 = *(const short8*)(RB); \
    const short8 a1 = *(const short8*)((RB) + 512); \
    const short8 aw = *(const short8*)(WRB); \
    LGK0; \
    STG; \
    acc00 = MFMA(a0, hf0, acc00); \
    acc10 = MFMA(a1, hf0, acc10); \
    aL0   = MFMA(aw, hf0, aL0); \
    acc01 = MFMA(a0, hf1, acc01); \
    acc11 = MFMA(a1, hf1, acc11); \
    aL1   = MFMA(aw, hf1, aL1); } while (0)

// W_ih iteration (u operand from u_buf)
#define KU(kk, RB, STG) do { \
    const short8 uf0 = *(const short8*)&u_buf[cur][c][((kk)-16)*32 + q*8]; \
    const short8 uf1 = *(const short8*)&u_buf[cur][16 + c][((kk)-16)*32 + q*8]; \
    const short8 a0 = *(const short8*)(RB); \
    const short8 a1 = *(const short8*)((RB) + 512); \
    LGK0; \
    STG; \
    acc00 = MFMA(a0, uf0, acc00); \
    acc10 = MFMA(a1, uf0, acc10); \
    acc01 = MFMA(a0, uf1, acc01); \
    acc11 = MFMA(a1, uf1, acc11); } while (0)

#define EPI(mt, bt, ACC, BS) do { \
    const unsigned lo = pack2bf(tanh_z(ACC[0] + BS[0]), \
                                tanh_z(ACC[1] + BS[1])); \
    const unsigned hi = pack2bf(tanh_z(ACC[2] + BS[2]), \
                                tanh_z(ACC[3] + BS[3])); \
    unsigned* d = (unsigned*)&h_buf[nxt][(bt)*16 + c][(2*w + (mt))*16 + q*4]; \
    d[0] = lo; d[1] = hi; } while (0)

// ---- main time-parallel recurrence kernel ----------------------------------
// 256 blocks = 128 t-chunks x 2 batch-halves. 1024 threads = 16 waves.
// Wave w: hidden A-tiles {2w,2w+1}, batch tiles {0,1}, accs acc00..acc11.
// A_ring[w][2 slots][2 tiles x 512 shorts]: slot kk&1 holds content kk; at
// kk we consume slot kk&1 then DMA content kk+2 (mod 18) into it -> contents
// for the NEXT step are staged before the barrier and stay in flight.
// vmcnt(N) counted per kk (N = op-count of content kk+1's stage; never 0 in
// steady state). Head waves (0-3) add a W_lin ring. One lgkm-only barrier
// per step.
__global__ __launch_bounds__(1024, 1) void rnn_kernel(
    const float* __restrict__ u, const float* __restrict__ b_ih,
    const float* __restrict__ b_hh, const float* __restrict__ b_lin,
    const unsigned short* __restrict__ Apk,
    const unsigned short* __restrict__ WihPk,
    const unsigned short* __restrict__ WlinPk,
    float* __restrict__ out)
{
  __shared__ __align__(16) unsigned short h_buf[2][M_B][ST_H];  // 66,560 B
  __shared__ __align__(16) unsigned short u_buf[2][M_B][ST_U];  //  9,216 B
  __shared__ __align__(16) unsigned short A_ring[16][2][1024];  // 65,536 B
  __shared__ __align__(16) unsigned short W_ring[4][2][512];    //  8,192 B

  const int tid = threadIdx.x;
  const int w = tid >> 6, lane = tid & 63, q = lane >> 4, c = lane & 15;
  const int bh = blockIdx.x >> 7;            // batch half (0/1)
  const int t0 = (blockIdx.x & 127) * L_CH;  // t-chunk origin
  const int B0 = bh * M_B;                   // global batch row base
  const bool hw = (w < 4);                   // head wave (one per SIMD)
  const int lt = w & 3;                      // head W_lin tile (valid when hw)

  // biases in registers (prescaled by K2); b_lin raw
  f32x4 bsum0, bsum1;
  {
    const int n0 = (2 * w) * 16 + q * 4;
    const f32x4 b0 = *(const f32x4*)(b_ih + n0) + *(const f32x4*)(b_hh + n0);
    bsum0 = (f32x4){b0[0] * K2f, b0[1] * K2f, b0[2] * K2f, b0[3] * K2f};
    const int n1 = (2 * w + 1) * 16 + q * 4;
    const f32x4 b1 = *(const f32x4*)(b_ih + n1) + *(const f32x4*)(b_hh + n1);
    bsum1 = (f32x4){b1[0] * K2f, b1[1] * K2f, b1[2] * K2f, b1[3] * K2f};
  }
  const f32x4 blin4 = *(const f32x4*)(b_lin + lt * 16 + q * 4);

  // pointers: global per-lane sources, LDS ring bases
  const unsigned short* apG = Apk    + ((size_t)(2 * w) * 64 + lane) * 8;
  const unsigned short* wpG = WihPk  + ((size_t)(2 * w) * 64 + lane) * 8;
  const unsigned short* lpG = WlinPk + ((size_t)lt * 64 + lane) * 8;
  unsigned short* sdA0 = &A_ring[w][0][0];
  unsigned short* sdA1 = &A_ring[w][1][0];
  unsigned short* sdW0 = &W_ring[lt][0][0];
  unsigned short* sdW1 = &W_ring[lt][1][0];
  const unsigned short* rbA0 = &A_ring[w][0][lane * 8];
  const unsigned short* rbA1 = &A_ring[w][1][lane * 8];
  const unsigned short* rbW0 = &W_ring[lt][0][lane * 8];
  const unsigned short* rbW1 = &W_ring[lt][1][lane * 8];

  // prologue: prime ring contents 0,1 (drained by the full __syncthreads)
  ST_A(0, sdA0); ST_A(1, sdA1);
  if (hw) { ST_L(0, sdW0); ST_L(1, sdW1); }

  for (int i = tid; i < M_B * ST_H / 2; i += 1024) ((unsigned*)h_buf[0])[i] = 0;
  float upC0, upC1;   // u for next epilogue (held one full step)
  {    // stage u for step 0 + prefetch for step 0's epilogue
    int t = t0 - W_UP; if (t < 0) t = 0;
    const int row = tid >> 5, cb = (tid & 31) * 2;
    const float* src = u + ((size_t)(B0 + row) * T_LEN + t) * N_IN + cb;
    *(unsigned*)&u_buf[0][row][cb] = pack2bf(src[0], src[1]);
    int t1 = t0 - W_UP + 1; t1 = t1 < 0 ? 0 : (t1 > T_LEN - 1 ? T_LEN - 1 : t1);
    const f32x2 v = *(const f32x2*)(u + ((size_t)(B0 + row) * T_LEN + t1) * N_IN + cb);
    upC0 = v[0]; upC1 = v[1];
  }
  __syncthreads();   // full barrier (drains prologue DMAs + loads)

  for (int s = 0; s < S_FULL; s++) {
    const int cur = s & 1, nxt = cur ^ 1;

    f32x4 acc00 = {0.f, 0.f, 0.f, 0.f}, acc01 = {0.f, 0.f, 0.f, 0.f};
    f32x4 acc10 = {0.f, 0.f, 0.f, 0.f}, acc11 = {0.f, 0.f, 0.f, 0.f};

    if (hw) {
      f32x4 aL0 = {0.f, 0.f, 0.f, 0.f}, aL1 = {0.f, 0.f, 0.f, 0.f};
      // waits = op-count of content kk+1's stage (3 for A+aw, 2 for W_ih),
      // +1 at kk=1 for the post-loop u-load of the previous step.
      VMW(3); KAH(0,  rbA0, rbW0, ST_A(2,  sdA0); ST_L(2,  sdW0));
      VMW(4); KAH(1,  rbA1, rbW1, ST_A(3,  sdA1); ST_L(3,  sdW1));
      VMW(3); KAH(2,  rbA0, rbW0, ST_A(4,  sdA0); ST_L(4,  sdW0));
      VMW(3); KAH(3,  rbA1, rbW1, ST_A(5,  sdA1); ST_L(5,  sdW1));
      VMW(3); KAH(4,  rbA0, rbW0, ST_A(6,  sdA0); ST_L(6,  sdW0));
      VMW(3); KAH(5,  rbA1, rbW1, ST_A(7,  sdA1); ST_L(7,  sdW1));
      VMW(3); KAH(6,  rbA0, rbW0, ST_A(8,  sdA0); ST_L(8,  sdW0));
      VMW(3); KAH(7,  rbA1, rbW1, ST_A(9,  sdA1); ST_L(9,  sdW1));
      VMW(3); KAH(8,  rbA0, rbW0, ST_A(10, sdA0); ST_L(10, sdW0));
      VMW(3); KAH(9,  rbA1, rbW1, ST_A(11, sdA1); ST_L(11, sdW1));
      VMW(3); KAH(10, rbA0, rbW0, ST_A(12, sdA0); ST_L(12, sdW0));
      VMW(3); KAH(11, rbA1, rbW1, ST_A(13, sdA1); ST_L(13, sdW1));
      VMW(3); KAH(12, rbA0, rbW0, ST_A(14, sdA0); ST_L(14, sdW0));
      VMW(3); KAH(13, rbA1, rbW1, ST_A(15, sdA1); ST_L(15, sdW1));
      VMW(3); KAH(14, rbA0, rbW0, ST_W(0, sdA0));
      VMW(2); KAH(15, rbA1, rbW1, ST_W(1, sdA1));
      VMW(2); KU(16, rbA0, ST_A(0, sdA0); ST_L(0, sdW0));
      VMW(3); KU(17, rbA1, ST_A(1, sdA1); ST_L(1, sdW1));
      // head store: out_t = W_lin*h^s + b_lin, t = t0 + s - W_UP - 1
      if (s > W_UP) {
        const int t = t0 + s - W_UP - 1;
        const f32x4 r0 = aL0 + blin4;
        float* op0 = out + ((size_t)(B0 + c) * T_LEN + t) * N_OUT + lt * 16 + q * 4;
        *(f32x4*)op0 = r0;
        const f32x4 r1 = aL1 + blin4;
        float* op1 = out + ((size_t)(B0 + 16 + c) * T_LEN + t) * N_OUT + lt * 16 + q * 4;
        *(f32x4*)op1 = r1;
      }
    } else {
      VMW(2); KA(0,  rbA0, ST_A(2,  sdA0));
      VMW(3); KA(1,  rbA1, ST_A(3,  sdA1));
      VMW(2); KA(2,  rbA0, ST_A(4,  sdA0));
      VMW(2); KA(3,  rbA1, ST_A(5,  sdA1));
      VMW(2); KA(4,  rbA0, ST_A(6,  sdA0));
      VMW(2); KA(5,  rbA1, ST_A(7,  sdA1));
      VMW(2); KA(6,  rbA0, ST_A(8,  sdA0));
      VMW(2); KA(7,  rbA1, ST_A(9,  sdA1));
      VMW(2); KA(8,  rbA0, ST_A(10, sdA0));
      VMW(2); KA(9,  rbA1, ST_A(11, sdA1));
      VMW(2); KA(10, rbA0, ST_A(12, sdA0));
      VMW(2); KA(11, rbA1, ST_A(13, sdA1));
      VMW(2); KA(12, rbA0, ST_A(14, sdA0));
      VMW(2); KA(13, rbA1, ST_A(15, sdA1));
      VMW(2); KA(14, rbA0, ST_W(0, sdA0));
      VMW(2); KA(15, rbA1, ST_W(1, sdA1));
      VMW(2); KU(16, rbA0, ST_A(0, sdA0));
      VMW(2); KU(17, rbA1, ST_A(1, sdA1));
    }

    // post-loop: prefetch u for NEXT step's epilogue (one full step of slack
    // -> its HBM latency never stalls a counted wait or this epilogue)
    float upN0, upN1;
    {
      int tn = t0 - W_UP + s + 2;
      tn = tn < 0 ? 0 : (tn > T_LEN - 1 ? T_LEN - 1 : tn);
      const int row = tid >> 5, cb = (tid & 31) * 2;
      const f32x2 v = *(const f32x2*)(u + ((size_t)(B0 + row) * T_LEN + tn) * N_IN + cb);
      upN0 = v[0]; upN1 = v[1];
    }

    // ---- epilogue: h_new = tanh_z(acc + bias) -> h_buf[nxt] (b64 writes) ----
    EPI(0, 0, acc00, bsum0);
    EPI(0, 1, acc01, bsum0);
    EPI(1, 0, acc10, bsum1);
    EPI(1, 1, acc11, bsum1);
    {
      const int row = tid >> 5, cb = (tid & 31) * 2;
      *(unsigned*)&u_buf[nxt][row][cb] = pack2bf(upC0, upC1);
    }
    upC0 = upN0; upC1 = upN1;
    step_barrier();   // lgkm-only: ring DMAs for the next step stay in flight
  }

  // ---- final head-only step: waves 0-3 consume h^21 (buf [S_FULL&1]) ----
  if (hw) {
    const int cf = S_FULL & 1;
    f32x4 aL0 = {0.f, 0.f, 0.f, 0.f}, aL1 = {0.f, 0.f, 0.f, 0.f};
#define KK_FIN(kk) do { \
      const short8 aw  = *(const short8*)(lpG + (size_t)(kk) * 2048); \
      const short8 hf0 = *(const short8*)&h_buf[cf][c][(kk)*32 + q*8]; \
      const short8 hf1 = *(const short8*)&h_buf[cf][16 + c][(kk)*32 + q*8]; \
      aL0 = MFMA(aw, hf0, aL0); \
      aL1 = MFMA(aw, hf1, aL1); } while (0)
    KK_FIN(0);  KK_FIN(1);  KK_FIN(2);  KK_FIN(3);
    KK_FIN(4);  KK_FIN(5);  KK_FIN(6);  KK_FIN(7);
    KK_FIN(8);  KK_FIN(9);  KK_FIN(10); KK_FIN(11);
    KK_FIN(12); KK_FIN(13); KK_FIN(14); KK_FIN(15);
#undef KK_FIN
    const int t = t0 + L_CH - 1;
    const f32x4 r0 = aL0 + blin4;
    float* op0 = out + ((size_t)(B0 + c) * T_LEN + t) * N_OUT + lt * 16 + q * 4;
    *(f32x4*)op0 = r0;
    const f32x4 r1 = aL1 + blin4;
    float* op1 = out + ((size_t)(B0 + 16 + c) * T_LEN + t) * N_OUT + lt * 16 + q * 4;
    *(f32x4*)op1 = r1;
  }
}

extern "C" void kernel_launch(void* const* d_in, const int* in_sizes, int n_in,
                              void* d_out, int out_size, void* d_ws, size_t ws_size,
                              hipStream_t stream) {
  const float* u     = (const float*)d_in[0];
  const float* W_ih  = (const float*)d_in[1];
  const float* W_hh  = (const float*)d_in[2];
  const float* b_ih  = (const float*)d_in[3];
  const float* b_hh  = (const float*)d_in[4];
  const float* omega = (const float*)d_in[5];
  const float* W_lin = (const float*)d_in[6];
  const float* b_lin = (const float*)d_in[7];
  float* out = (float*)d_out;

  unsigned short* Apk    = (unsigned short*)d_ws;                 // 512*512 bf16
  unsigned short* WihPk  = Apk + (size_t)H_DIM * H_DIM;           // 512*64
  unsigned short* WlinPk = WihPk + (size_t)H_DIM * N_IN;          // 64*512

  pack_kernel<<<34, 256, 0, stream>>>(W_ih, W_hh, omega, W_lin, Apk, WihPk, WlinPk);
  rnn_kernel<<<(T_LEN / L_CH) * 2, 1024, 0, stream>>>(u, b_ih, b_hh, b_lin,
                                                      Apk, WihPk, WlinPk, out);
}